// Round 3
// baseline (169.049 us; speedup 1.0000x reference)
//
#include <hip/hip_runtime.h>
#include <math.h>

#define BATCH 2
#define LSEQ  2048
#define DIMM  1024
#define NH    16
#define DH    64

typedef unsigned short ushortT;
typedef __attribute__((ext_vector_type(8))) short bf16x8;
typedef __attribute__((ext_vector_type(4))) float f32x4;

#define MFMA16(a, b, c) __builtin_amdgcn_mfma_f32_16x16x32_bf16((a), (b), (c), 0, 0, 0)

// scale folded into q columns of W_qkv: (1/sqrt(64)) * log2(e)
#define QSCALE 0.18033688011112042f

__device__ __forceinline__ ushortT f2bf(float f) {
    unsigned u = __float_as_uint(f);
    u += 0x7fffu + ((u >> 16) & 1u);   // RNE
    return (ushortT)(u >> 16);
}

// async global->LDS, 16B per lane. LDS dest is wave-uniform base + lane*16.
__device__ __forceinline__ void gll16(const ushortT* g, ushortT* l) {
    ushortT* gm = const_cast<ushortT*>(g);
    __builtin_amdgcn_global_load_lds(
        (__attribute__((address_space(1))) void*)gm,
        (__attribute__((address_space(3))) void*)l, 16, 0, 0);
}

// ---------------------------------------------------------------------------
// Fused prep: blocks [0,4096): x fp32->bf16; blocks [4096,8192): weight
// transposes W[K][N] fp32 -> Wt[N][K] bf16 (q-cols of W_qkv scaled by QSCALE).
// ---------------------------------------------------------------------------
__global__ __launch_bounds__(256) void prep(
    const float* __restrict__ x, ushortT* __restrict__ xb,
    const float* __restrict__ Wqkv, const float* __restrict__ Wout,
    ushortT* __restrict__ wqt, ushortT* __restrict__ wot)
{
    __shared__ float T[32][33];
    const int bx = blockIdx.x;
    const int tid = threadIdx.x;
    if (bx < 4096) {
        int i = bx * 256 + tid;
        float4 v = ((const float4*)x)[i];
        ushort4 o;
        o.x = f2bf(v.x); o.y = f2bf(v.y); o.z = f2bf(v.z); o.w = f2bf(v.w);
        ((ushort4*)xb)[i] = o;
        return;
    }
    const int id2 = bx - 4096;
    const int nb = id2 & 127, kb = id2 >> 7;
    const float* W; ushortT* Wt; int N, n0, nlimit;
    if (nb < 96) { W = Wqkv; Wt = wqt; N = 3 * DIMM; n0 = nb * 32; nlimit = DIMM; }
    else         { W = Wout; Wt = wot; N = DIMM;     n0 = (nb - 96) * 32; nlimit = 0; }
    const int k0 = kb * 32;
    const int c = tid & 31, r0 = tid >> 5;
#pragma unroll
    for (int p = 0; p < 4; ++p)
        T[r0 + 8 * p][c] = W[(size_t)(k0 + r0 + 8 * p) * N + n0 + c];
    __syncthreads();
#pragma unroll
    for (int p = 0; p < 4; ++p) {
        int rr = r0 + 8 * p;
        float v = T[c][rr];
        if (n0 + rr < nlimit) v *= QSCALE;
        Wt[(size_t)(n0 + rr) * DIMM + k0 + c] = f2bf(v);
    }
}

// ---------------------------------------------------------------------------
// R12: 256x256 4-phase mainloop with TRUE COUNTED vmcnt (T3+T4+T5).
// R11 post-mortem: per-tile vmcnt(0) drain == the measured "drain0 ==
// 1-phase" regime (m218) -> only ~10% gain. Fix: staging units split along
// K so consumption order is wave-uniform:
//   unit0 = A[k:k+32), unit1 = B[k:k+32), unit2 = A[+32], unit3 = B[+32]
// (each 256 rows x 32 cols = 16 KB = 2 loads/thread). Phases 0-1 consume
// units 0,1; phases 2-3 consume units 2,3 (all waves identically).
// Stage unit u of tile t+1 at phase u of tile t. In-order vmcnt retirement:
//   end P3 of t: outstanding=[u0..u3 of t+1] -> vmcnt(4) retires u0,u1 ✓
//   end P1 of t: outstanding=[u2,u3 of t, u0,u1 of t+1] -> vmcnt(4)
//                retires u2,u3 of t ✓   (never 0 in the main loop)
// Swizzle: LDS (row r, 16B-chunk c) holds global chunk c ^ ((r>>1)&3);
// reader chunk = quad ^ ((li>>1)&3) -> 2 lanes/bank-group (free, m136).
// Per-acc accumulation order (k0 then k1) is bitwise identical to R11.
// Phase: {ds_read frags | stage 1 unit | barrier | lgkmcnt(0) | setprio(1)
//         16xMFMA setprio(0) | [counted vmcnt] | barrier}.
// ---------------------------------------------------------------------------
template<bool SWAP>
__device__ __forceinline__ void mainloop256(
    const ushortT* __restrict__ A, const ushortT* __restrict__ Bt,
    ushortT S[2][4][8192], int bm, int bn, int w, int lane, f32x4 acc[8][4])
{
    const int quad = lane >> 4, li = lane & 15;
    const int wm = w >> 2, wn = w & 3;
    const int cfrag = ((quad ^ ((li >> 1) & 3))) * 8;   // frag chunk in 32-col unit
    // staging geometry: lane -> row w*16 + (lane>>2) (+128 pass1), chunk lane&3;
    // source chunk = (lane&3) ^ ((row>>1)&3); row>>1 bits from lane>>3 only.
    const int srow = w * 16 + (lane >> 2);
    const int sch = (((lane >> 3) & 3) ^ (lane & 3)) * 8;
    const ushortT* pA = A  + (size_t)(bm + srow) * DIMM + sch;
    const ushortT* pB = Bt + (size_t)(bn + srow) * DIMM + sch;
    const int ldst0 = (w * 16) * 32;          // wave-uniform LDS dest (shorts)
    const int ldst1 = (128 + w * 16) * 32;
    const int RU = SWAP ? 1 : 0, CU2 = SWAP ? 0 : 1;   // row/col operand units
    const int rbase = wm * 128, cbase = wn * 64;
    bf16x8 af[4], bfr[4];
    int koff;

#define STAGE_U(U) do { \
        const ushortT* g_ = (((U) & 1) ? pB : pA) + koff + ((U) >> 1) * 32; \
        gll16(g_,             &Snext[(U)][ldst0]); \
        gll16(g_ + 128 * DIMM, &Snext[(U)][ldst1]); \
    } while (0)

    {   // prologue: stage K-tile 0 fully, drain (one-time stall)
        ushortT (*Snext)[8192] = S[0];
        koff = 0;
        STAGE_U(0); STAGE_U(1); STAGE_U(2); STAGE_U(3);
        __syncthreads();   // vmcnt(0) lgkmcnt(0) + barrier
    }
    koff = 64;

#define PHASE(P, STG, WAITN) do { \
        { \
            const ushortT* RSU = &S[CUR][RU + (((P) >> 1) << 1)][0]; \
            const int ro_ = rbase + (((P) & 1) ? 64 : 0); \
            _Pragma("unroll") \
            for (int rt_ = 0; rt_ < 4; ++rt_) \
                af[rt_] = *(const bf16x8*)&RSU[(ro_ + 16 * rt_ + li) * 32 + cfrag]; \
            if (((P) & 1) == 0) { \
                const ushortT* CSU = &S[CUR][CU2 + (((P) >> 1) << 1)][0]; \
                _Pragma("unroll") \
                for (int ct_ = 0; ct_ < 4; ++ct_) \
                    bfr[ct_] = *(const bf16x8*)&CSU[(cbase + 16 * ct_ + li) * 32 + cfrag]; \
            } \
        } \
        if (STG) { STAGE_U(P); } \
        __builtin_amdgcn_s_barrier(); \
        asm volatile("s_waitcnt lgkmcnt(0)" ::: "memory"); \
        __builtin_amdgcn_sched_barrier(0); \
        __builtin_amdgcn_s_setprio(1); \
        { \
            const int rb_ = ((P) & 1) * 4; \
            _Pragma("unroll") \
            for (int rt_ = 0; rt_ < 4; ++rt_) { \
                _Pragma("unroll") \
                for (int ct_ = 0; ct_ < 4; ++ct_) \
                    acc[rb_ + rt_][ct_] = MFMA16(af[rt_], bfr[ct_], acc[rb_ + rt_][ct_]); \
            } \
        } \
        __builtin_amdgcn_s_setprio(0); \
        if ((WAITN) == 4) { asm volatile("s_waitcnt vmcnt(4)" ::: "memory"); } \
        else if ((WAITN) == 0) { asm volatile("s_waitcnt vmcnt(0)" ::: "memory"); } \
        __builtin_amdgcn_sched_barrier(0); \
        __builtin_amdgcn_s_barrier(); \
    } while (0)

#define KTILE(CUR_, STG) do { \
        const int CUR = (CUR_); \
        ushortT (*Snext)[8192] = S[(CUR_) ^ 1]; (void)Snext; \
        PHASE(0, STG, -1); \
        PHASE(1, STG, (STG) ? 4 : 0); \
        PHASE(2, STG, -1); \
        PHASE(3, STG, (STG) ? 4 : -1); \
        koff += 64; \
    } while (0)

    // K = 1024 -> 16 K-tiles; tile t uses buffer t&1; stage tile t+1 while
    // computing tile t with counted vmcnt(4). Last tile peeled (no staging;
    // its P1 wait drains the <=4 loads issued a full tile earlier: free).
#pragma unroll 1
    for (int it = 0; it < 7; ++it) { KTILE(0, 1); KTILE(1, 1); }
    KTILE(0, 1);                                     // tile 14 stages tile 15
    KTILE(1, 0);                                     // tile 15
#undef KTILE
#undef PHASE
#undef STAGE_U
}

// ---------------------------------------------------------------------------
// GEMM1: qkv projection, 256^2 tiles, 512 threads, 192 blocks (1/CU).
// q/k via swapped mainloop -> vectorized [b,h,l,d] stores; v via normal
// mainloop -> vectorized transposed [b,h,d,l] stores.
// ---------------------------------------------------------------------------
__global__ __launch_bounds__(512, 2) void gemm_qkv(
    const ushortT* __restrict__ A, const ushortT* __restrict__ Bt,
    const float* __restrict__ bias,
    ushortT* __restrict__ qb, ushortT* __restrict__ kb, ushortT* __restrict__ vt)
{
    __shared__ __align__(16) ushortT S[2][4][8192];   // 128 KiB
    const int tid = threadIdx.x;
    const int w = tid >> 6, lane = tid & 63, quad = lane >> 4, li = lane & 15;
    const int wm = w >> 2, wn = w & 3;
    // bijective XCD swizzle (192 % 8 == 0): each XCD gets 24 consecutive
    // tiles = 2 full M-panels -> A-panel L2 reuse.
    const int bid = blockIdx.x;
    const int nbid = (bid & 7) * 24 + (bid >> 3);
    const int bx = nbid % 12, by = nbid / 12;
    const int bm = by * 256, bn = bx * 256;
    const int which = bx >> 2;                        // 0=q 1=k 2=v (uniform)
    const f32x4 z4 = {0.f, 0.f, 0.f, 0.f};
    f32x4 acc[8][4];
#pragma unroll
    for (int i = 0; i < 8; ++i)
#pragma unroll
        for (int j = 0; j < 4; ++j) acc[i][j] = z4;

    if (which == 2) {
        mainloop256<false>(A, Bt, S, bm, bn, w, lane, acc);
#pragma unroll
        for (int rt = 0; rt < 8; ++rt) {
            const int m = bm + wm * 128 + (rt >> 2) * 64 + (rt & 3) * 16 + quad * 4;
            const int b = m >> 11, l = m & 2047;
#pragma unroll
            for (int ct = 0; ct < 4; ++ct) {
                const int n = bn + wn * 64 + 16 * ct + li;
                const int nn = n & 1023;
                const int h = nn >> 6, dd = nn & 63;
                const float bterm = bias[n];
                ushort4 o4;
                o4.x = f2bf(acc[rt][ct][0] + bterm);
                o4.y = f2bf(acc[rt][ct][1] + bterm);
                o4.z = f2bf(acc[rt][ct][2] + bterm);
                o4.w = f2bf(acc[rt][ct][3] + bterm);
                *(ushort4*)(vt + ((size_t)(b * NH + h) * DH + dd) * LSEQ + l) = o4;
            }
        }
    } else {
        mainloop256<true>(A, Bt, S, bm, bn, w, lane, acc);
        const float bscale = (which == 0) ? QSCALE : 1.0f;
        ushortT* dst = (which == 0) ? qb : kb;
#pragma unroll
        for (int rt = 0; rt < 8; ++rt) {
            const int n0 = bn + wm * 128 + (rt >> 2) * 64 + (rt & 3) * 16 + quad * 4;
            const int nn0 = n0 & 1023;
            const int h = nn0 >> 6, dd = nn0 & 63;
            const float4 bv = *(const float4*)&bias[n0];
#pragma unroll
            for (int ct = 0; ct < 4; ++ct) {
                const int m = bm + wn * 64 + 16 * ct + li;
                const int b = m >> 11, l = m & 2047;
                ushort4 o4;
                o4.x = f2bf(acc[rt][ct][0] + bv.x * bscale);
                o4.y = f2bf(acc[rt][ct][1] + bv.y * bscale);
                o4.z = f2bf(acc[rt][ct][2] + bv.z * bscale);
                o4.w = f2bf(acc[rt][ct][3] + bv.w * bscale);
                *(ushort4*)(dst + ((size_t)(b * NH + h) * LSEQ + l) * DH + dd) = o4;
            }
        }
    }
}

// ---------------------------------------------------------------------------
// GEMM2: out = o @ W_out + b_out (fp32 out). 128(M)x64(N) tiles, BK=128,
// DMA staging (R7 version — register prefetch spilled, see R8).
// ---------------------------------------------------------------------------
__global__ __launch_bounds__(256) void gemm_out(
    const ushortT* __restrict__ A, const ushortT* __restrict__ Bt,
    const float* __restrict__ bias, float* __restrict__ out)
{
    __shared__ __align__(16) ushortT As[128 * 128];   // 32 KB
    __shared__ __align__(16) ushortT Bs[64 * 128];    // 16 KB
    const int tid = threadIdx.x;
    const int w = tid >> 6, lane = tid & 63, quad = lane >> 4, li = lane & 15;
    const int bm = blockIdx.y * 128, bn = blockIdx.x * 64;
    const int wm = (w & 1) * 64, wn = (w >> 1) * 32;
    const int r4 = lane >> 4, c16 = lane & 15;
    const int sw = li & 7;

    const ushortT* pa[8]; ushortT* la[8];
#pragma unroll
    for (int j = 0; j < 8; ++j) {
        int Bi = w + 4 * j;
        int row = Bi * 4 + r4;
        int cxA = c16 ^ ((Bi & 1) * 4 + r4);       // == c16 ^ (row&7)
        pa[j] = A + (size_t)(bm + row) * DIMM + cxA * 8;
        la[j] = As + Bi * 512;
    }
    const ushortT* pb[4]; ushortT* lb[4];
#pragma unroll
    for (int j = 0; j < 4; ++j) {
        int Bi = w + 4 * j;
        int row = Bi * 4 + r4;
        int cxB = c16 ^ ((Bi & 1) * 4 + r4);
        pb[j] = Bt + (size_t)(bn + row) * DIMM + cxB * 8;
        lb[j] = Bs + Bi * 512;
    }

    const f32x4 z4 = {0.f, 0.f, 0.f, 0.f};
    f32x4 acc[4][2];
#pragma unroll
    for (int i = 0; i < 4; ++i) { acc[i][0] = z4; acc[i][1] = z4; }

    for (int k0 = 0; k0 < DIMM; k0 += 128) {
#pragma unroll
        for (int j = 0; j < 8; ++j) { gll16(pa[j], la[j]); pa[j] += 128; }
#pragma unroll
        for (int j = 0; j < 4; ++j) { gll16(pb[j], lb[j]); pb[j] += 128; }
        __syncthreads();
#pragma unroll
        for (int g = 0; g < 2; ++g) {
            const int s0 = (g * 8 + (quad ^ sw)) * 8;
            const int s1 = (g * 8 + ((quad + 4) ^ sw)) * 8;
            bf16x8 bfr[2][2];
#pragma unroll
            for (int t = 0; t < 2; ++t) {
                int R = wn + 16 * t + li;
                bfr[t][0] = *(const bf16x8*)&Bs[R * 128 + s0];
                bfr[t][1] = *(const bf16x8*)&Bs[R * 128 + s1];
            }
#pragma unroll
            for (int rt = 0; rt < 4; ++rt) {
                int R = wm + 16 * rt + li;
                bf16x8 a0 = *(const bf16x8*)&As[R * 128 + s0];
                bf16x8 a1 = *(const bf16x8*)&As[R * 128 + s1];
#pragma unroll
                for (int ct = 0; ct < 2; ++ct) {
                    acc[rt][ct] = MFMA16(a0, bfr[ct][0], acc[rt][ct]);
                    acc[rt][ct] = MFMA16(a1, bfr[ct][1], acc[rt][ct]);
                }
            }
        }
        __syncthreads();
    }
#pragma unroll
    for (int rt = 0; rt < 4; ++rt) {
#pragma unroll
        for (int ct = 0; ct < 2; ++ct) {
            int n = bn + wn + 16 * ct + li;
            float bterm = bias[n];
#pragma unroll
            for (int r = 0; r < 4; ++r) {
                int m = bm + wm + 16 * rt + quad * 4 + r;
                out[(size_t)m * DIMM + n] = acc[rt][ct][r] + bterm;
            }
        }
    }
}

// ---------------------------------------------------------------------------
// Flash attention, block-causal, transposed inner math, 128-KEY TILES.
// R9: softmax denominators computed by MFMA (A = ones, B = P^T fragments
// already loaded for PV) — removes the per-element AND+fadd chain and the
// final shuffle reduction; sum is exactly consistent with stored bf16 P.
// P packing via v_perm_b32 (1 op per pair).
// ---------------------------------------------------------------------------
__global__ __launch_bounds__(256, 2) void attn(
    const ushortT* __restrict__ qg, const ushortT* __restrict__ kg,
    const ushortT* __restrict__ vtg, ushortT* __restrict__ og)
{
    __shared__ __align__(16) ushortT Kbuf[2][8192];   // [p][half*4096 + blk*512]
    __shared__ __align__(16) ushortT Vbuf[2][8192];   // [d][l] halves
    __shared__ __align__(16) ushortT PsT[4096];       // 4 waves x 2 KB

    const int tid = threadIdx.x;
    const int w = tid >> 6, lane = tid & 63, quad = lane >> 4, li = lane & 15;
    const int id = blockIdx.x;                 // 0..511
    const int qt = (id < 256) ? (15 - (id >> 5)) : ((id - 256) >> 5);
    const int bhid = id & 31;
    const int b = bhid >> 4, h = bhid & 15;
    const size_t bh = (size_t)b * NH + h;
    const ushortT* qbase = qg + (bh * LSEQ + qt * 128) * DH;
    const ushortT* kbase = kg + bh * LSEQ * DH;
    const ushortT* vbase = vtg + bh * DH * LSEQ;
    ushortT* obase = og + ((size_t)b * LSEQ + qt * 128) * DIMM + h * DH;
    const f32x4 z4 = {0.f, 0.f, 0.f, 0.f};

    // ones A-fragment for the denominator MFMA (bf16 1.0 = 0x3F80)
    const short ONE = (short)0x3F80;
    const bf16x8 onesA = {ONE, ONE, ONE, ONE, ONE, ONE, ONE, ONE};

    // staging lane geometry (within each 8-row x 1KB DMA block)
    const int r8 = lane >> 3, c8 = lane & 7, cx = c8 ^ r8;

    bf16x8 qf[2][2];
#pragma unroll
    for (int band = 0; band < 2; ++band) {
        int row = 32 * w + 16 * band + li;
        qf[band][0] = *(const bf16x8*)(qbase + (size_t)row * DH + quad * 8);
        qf[band][1] = *(const bf16x8*)(qbase + (size_t)row * DH + 32 + quad * 8);
    }
    f32x4 oaccT[2][4];     // [band][dt]: O^T, lane owns qrow=li
    f32x4 lsacc[2];        // denominator acc (all 4 comps equal per lane)
#pragma unroll
    for (int i = 0; i < 2; ++i) {
        lsacc[i] = z4;
#pragma unroll
        for (int j = 0; j < 4; ++j) oaccT[i][j] = z4;
    }

    const int nt = qt + 1;                 // 128-key tiles
    // stage tile 0 (8 gll16/wave: 2 halves x {K,V} x 2 blocks)
#pragma unroll
    for (int s = 0; s < 2; ++s)
#pragma unroll
        for (int jj = 0; jj < 2; ++jj) {
            int B = w + 4 * jj;
            gll16(kbase + (size_t)(s * 64 + B * 8 + r8) * DH + cx * 8,
                  &Kbuf[0][s * 4096 + B * 512]);
            gll16(vbase + (size_t)(B * 8 + r8) * LSEQ + s * 64 + cx * 8,
                  &Vbuf[0][s * 4096 + B * 512]);
        }
    __syncthreads();

    const int sw = li & 7;
    const int pbase = w * 1024 + li * 8;

    for (int t = 0; t < nt; ++t) {
        const int p = t & 1;
        if (t + 1 < nt) {   // DMA next 128-key tile; drains at loop barrier
#pragma unroll
            for (int s = 0; s < 2; ++s)
#pragma unroll
                for (int jj = 0; jj < 2; ++jj) {
                    int B = w + 4 * jj;
                    gll16(kbase + (size_t)((t + 1) * 128 + s * 64 + B * 8 + r8) * DH + cx * 8,
                          &Kbuf[1 - p][s * 4096 + B * 512]);
                    gll16(vbase + (size_t)(B * 8 + r8) * LSEQ + (t + 1) * 128 + s * 64 + cx * 8,
                          &Vbuf[1 - p][s * 4096 + B * 512]);
                }
        }

#pragma unroll
        for (int s = 0; s < 2; ++s) {
            const ushortT* Kb = &Kbuf[p][s * 4096];
            const ushortT* Vb = &Vbuf[p][s * 4096];
            bf16x8 kf[4][2], vf[4][2];
#pragma unroll
            for (int ct = 0; ct < 4; ++ct) {
                int R = 16 * ct + li;
                kf[ct][0] = *(const bf16x8*)&Kb[R * 64 + (quad ^ sw) * 8];
                kf[ct][1] = *(const bf16x8*)&Kb[R * 64 + ((quad + 4) ^ sw) * 8];
            }
#pragma unroll
            for (int dt = 0; dt < 4; ++dt) {
                int R = 16 * dt + li;
                vf[dt][0] = *(const bf16x8*)&Vb[R * 64 + (quad ^ sw) * 8];
                vf[dt][1] = *(const bf16x8*)&Vb[R * 64 + ((quad + 4) ^ sw) * 8];
            }
#pragma unroll
            for (int band = 0; band < 2; ++band) {
                // S^T = K Q^T (pre-scaled, log2 domain)
                f32x4 sa[4];
#pragma unroll
                for (int ct = 0; ct < 4; ++ct) {
                    sa[ct] = MFMA16(kf[ct][0], qf[band][0], z4);
                    sa[ct] = MFMA16(kf[ct][1], qf[band][1], sa[ct]);
                }
                // exp2, pack 4 keys (RTZ bf16) via v_perm, one b64 write
#pragma unroll
                for (int ct = 0; ct < 4; ++ct) {
                    unsigned u0 = __float_as_uint(__builtin_amdgcn_exp2f(sa[ct][0]));
                    unsigned u1 = __float_as_uint(__builtin_amdgcn_exp2f(sa[ct][1]));
                    unsigned u2 = __float_as_uint(__builtin_amdgcn_exp2f(sa[ct][2]));
                    unsigned u3 = __float_as_uint(__builtin_amdgcn_exp2f(sa[ct][3]));
                    uint2 pk;
                    pk.x = __builtin_amdgcn_perm(u1, u0, 0x07060302u);
                    pk.y = __builtin_amdgcn_perm(u3, u2, 0x07060302u);
                    *(uint2*)&PsT[pbase + (2 * ct + (quad >> 1)) * 128 + (quad & 1) * 4] = pk;
                }
                // read P^T fragments once; use for BOTH denominator and PV
                bf16x8 pt0 = *(const bf16x8*)&PsT[pbase + quad * 128];
                bf16x8 pt1 = *(const bf16x8*)&PsT[pbase + (4 + quad) * 128];
                lsacc[band] = MFMA16(onesA, pt0, lsacc[band]);   // denom += col-sums
                lsacc[band] = MFMA16(onesA, pt1, lsacc[band]);
#pragma unroll
                for (int dt = 0; dt < 4; ++dt) {
                    oaccT[band][dt] = MFMA16(vf[dt][0], pt0, oaccT[band][dt]);
                    oaccT[band][dt] = MFMA16(vf[dt][1], pt1, oaccT[band][dt]);
                }
            }
        }
        __syncthreads();   // DMA drained + all readers of buf[p] done
    }

    // ---- normalize (denominator complete per-lane), store O (ushort4 on d) ----
#pragma unroll
    for (int band = 0; band < 2; ++band) {
        float inv = 1.0f / lsacc[band][0];
        int m = 32 * w + 16 * band + li;        // qrow
#pragma unroll
        for (int dt = 0; dt < 4; ++dt) {
            ushort4 o4;
            o4.x = f2bf(oaccT[band][dt][0] * inv);
            o4.y = f2bf(oaccT[band][dt][1] * inv);
            o4.z = f2bf(oaccT[band][dt][2] * inv);
            o4.w = f2bf(oaccT[band][dt][3] * inv);
            *(ushort4*)(obase + (size_t)m * DIMM + 16 * dt + quad * 4) = o4;
        }
    }
}

// ---------------------------------------------------------------------------
extern "C" void kernel_launch(void* const* d_in, const int* in_sizes, int n_in,
                              void* d_out, int out_size, void* d_ws, size_t ws_size,
                              hipStream_t stream)
{
    const float* x    = (const float*)d_in[0];
    const float* Wqkv = (const float*)d_in[1];
    const float* bqkv = (const float*)d_in[2];
    const float* Wout = (const float*)d_in[3];
    const float* bout = (const float*)d_in[4];

    const size_t M4 = (size_t)4 * 1024 * 1024;
    ushortT* ws  = (ushortT*)d_ws;
    ushortT* xb  = ws;                                  // 4M shorts
    ushortT* qb  = ws + M4;                             // 4M
    ushortT* kb  = ws + 2 * M4;                         // 4M
    ushortT* vt  = ws + 3 * M4;                         // 4M  [B,H,d,L]
    ushortT* ob  = ws + 4 * M4;                         // 4M  [B,L,H*d]
    ushortT* wqt = ws + 5 * M4;                         // 3M
    ushortT* wot = ws + 5 * M4 + (size_t)3 * 1024 * 1024;  // 1M

    prep<<<8192, 256, 0, stream>>>(x, xb, Wqkv, Wout, wqt, wot);
    gemm_qkv<<<dim3(192), 512, 0, stream>>>(xb, wqt, bqkv, qb, kb, vt);
    attn<<<dim3(512), 256, 0, stream>>>(qb, kb, vt, ob);
    gemm_out<<<dim3(16, 32), 256, 0, stream>>>(ob, wot, bout, (float*)d_out);
}

// Round 4
// 167.810 us; speedup vs baseline: 1.0074x; 1.0074x over previous
//
#include <hip/hip_runtime.h>
#include <math.h>

#define BATCH 2
#define LSEQ  2048
#define DIMM  1024
#define NH    16
#define DH    64

typedef unsigned short ushortT;
typedef __attribute__((ext_vector_type(8))) short bf16x8;
typedef __attribute__((ext_vector_type(4))) float f32x4;

#define MFMA16(a, b, c) __builtin_amdgcn_mfma_f32_16x16x32_bf16((a), (b), (c), 0, 0, 0)

// scale folded into q columns of W_qkv: (1/sqrt(64)) * log2(e)
#define QSCALE 0.18033688011112042f

__device__ __forceinline__ ushortT f2bf(float f) {
    unsigned u = __float_as_uint(f);
    u += 0x7fffu + ((u >> 16) & 1u);   // RNE
    return (ushortT)(u >> 16);
}

// async global->LDS, 16B per lane. LDS dest is wave-uniform base + lane*16.
__device__ __forceinline__ void gll16(const ushortT* g, ushortT* l) {
    ushortT* gm = const_cast<ushortT*>(g);
    __builtin_amdgcn_global_load_lds(
        (__attribute__((address_space(1))) void*)gm,
        (__attribute__((address_space(3))) void*)l, 16, 0, 0);
}

// ---------------------------------------------------------------------------
// Fused prep: blocks [0,4096): x fp32->bf16; blocks [4096,8192): weight
// transposes W[K][N] fp32 -> Wt[N][K] bf16 (q-cols of W_qkv scaled by QSCALE).
// ---------------------------------------------------------------------------
__global__ __launch_bounds__(256) void prep(
    const float* __restrict__ x, ushortT* __restrict__ xb,
    const float* __restrict__ Wqkv, const float* __restrict__ Wout,
    ushortT* __restrict__ wqt, ushortT* __restrict__ wot)
{
    __shared__ float T[32][33];
    const int bx = blockIdx.x;
    const int tid = threadIdx.x;
    if (bx < 4096) {
        int i = bx * 256 + tid;
        float4 v = ((const float4*)x)[i];
        ushort4 o;
        o.x = f2bf(v.x); o.y = f2bf(v.y); o.z = f2bf(v.z); o.w = f2bf(v.w);
        ((ushort4*)xb)[i] = o;
        return;
    }
    const int id2 = bx - 4096;
    const int nb = id2 & 127, kb = id2 >> 7;
    const float* W; ushortT* Wt; int N, n0, nlimit;
    if (nb < 96) { W = Wqkv; Wt = wqt; N = 3 * DIMM; n0 = nb * 32; nlimit = DIMM; }
    else         { W = Wout; Wt = wot; N = DIMM;     n0 = (nb - 96) * 32; nlimit = 0; }
    const int k0 = kb * 32;
    const int c = tid & 31, r0 = tid >> 5;
#pragma unroll
    for (int p = 0; p < 4; ++p)
        T[r0 + 8 * p][c] = W[(size_t)(k0 + r0 + 8 * p) * N + n0 + c];
    __syncthreads();
#pragma unroll
    for (int p = 0; p < 4; ++p) {
        int rr = r0 + 8 * p;
        float v = T[c][rr];
        if (n0 + rr < nlimit) v *= QSCALE;
        Wt[(size_t)(n0 + rr) * DIMM + k0 + c] = f2bf(v);
    }
}

// ---------------------------------------------------------------------------
// R13: mainloop reverted to R11 (measured best: total 168.1 µs).
// R12 post-mortem: counted-vmcnt K-split variant regressed (48.5 vs ~40 µs,
// MfmaUtil 19%); all three schedule variants (R0/R11/R12) pin at 19-21%
// MfmaUtil -> the phase-lockstep overlap is not reproducing on this kernel;
// keep the best-measured structure.
// 256x256, 8 waves (2M x 4N), BK=64, 128 KiB LDS double-buffer, 4 half-tiles
// per buffer (ht0/1 = A rows 0-127/128-255, ht2/3 = B). Staging issued early
// (phases 0,1), single vmcnt(0) drain at end of phase 3.
// ---------------------------------------------------------------------------
template<bool SWAP>
__device__ __forceinline__ void mainloop256(
    const ushortT* __restrict__ A, const ushortT* __restrict__ Bt,
    ushortT S[2][4][8192], int bm, int bn, int w, int lane, f32x4 acc[8][4])
{
    const int quad = lane >> 4, li = lane & 15;
    const int wm = w >> 2, wn = w & 3;
    const int sw = li & 7;
    const int s0 = (quad ^ sw) * 8, s1 = ((quad + 4) ^ sw) * 8;
    const int r8 = lane >> 3, c8 = lane & 7, cch = c8 ^ r8;
    const ushortT* sA = A  + (size_t)(bm + 16 * w + r8) * DIMM + cch * 8;
    const ushortT* sB = Bt + (size_t)(bn + 16 * w + r8) * DIMM + cch * 8;
    const int RSht = SWAP ? 2 + wm : wm;          // row-operand half-tile
    const int CSht = SWAP ? (wn >> 1) : 2 + (wn >> 1);  // col-operand half-tile
    const int cb64 = (wn & 1) * 64;               // row base within CS half-tile
    bf16x8 af[4][2], bfr[4][2];
    int koff = 0;

#define STAGE_HT(P) do { \
        const ushortT* sp_ = (((P) < 2) ? sA : sB) + ((P) & 1) * 128 * DIMM + koff; \
        gll16(sp_,            &Snext[(P)][(16 * w) * 64]); \
        gll16(sp_ + 8 * DIMM, &Snext[(P)][(16 * w + 8) * 64]); \
    } while (0)

    {   // prologue: stage K-tile 0 into S[0], full drain
        ushortT (*Snext)[8192] = S[0];
        STAGE_HT(0); STAGE_HT(1); STAGE_HT(2); STAGE_HT(3);
        __syncthreads();   // vmcnt(0) lgkmcnt(0) + barrier
    }
    koff = 64;

#define PHASE(P, STG) do { \
        if ((P) == 0 || (P) == 2) { \
            const int rh_ = ((P) == 2) ? 64 : 0; \
            _Pragma("unroll") \
            for (int rt_ = 0; rt_ < 4; ++rt_) { \
                const int R_ = rh_ + 16 * rt_ + li; \
                af[rt_][0] = *(const bf16x8*)&RS[R_ * 64 + s0]; \
                af[rt_][1] = *(const bf16x8*)&RS[R_ * 64 + s1]; \
            } \
        } \
        if ((P) == 0 || (P) == 1) { \
            _Pragma("unroll") \
            for (int c_ = 0; c_ < 2; ++c_) { \
                const int ct_ = (P) * 2 + c_; \
                const int R_ = cb64 + 16 * ct_ + li; \
                bfr[ct_][0] = *(const bf16x8*)&CS[R_ * 64 + s0]; \
                bfr[ct_][1] = *(const bf16x8*)&CS[R_ * 64 + s1]; \
            } \
        } \
        if (STG) { \
            if ((P) == 0) { STAGE_HT(0); STAGE_HT(1); } \
            if ((P) == 1) { STAGE_HT(2); STAGE_HT(3); } \
        } \
        __builtin_amdgcn_s_barrier(); \
        asm volatile("s_waitcnt lgkmcnt(0)" ::: "memory"); \
        __builtin_amdgcn_sched_barrier(0); \
        __builtin_amdgcn_s_setprio(1); \
        { \
            const int rb_ = ((P) >= 2) ? 4 : 0; \
            const int cb_ = ((P) == 1 || (P) == 2) ? 2 : 0; \
            _Pragma("unroll") \
            for (int rt_ = 0; rt_ < 4; ++rt_) { \
                _Pragma("unroll") \
                for (int c_ = 0; c_ < 2; ++c_) { \
                    acc[rb_ + rt_][cb_ + c_] = MFMA16(af[rt_][0], bfr[cb_ + c_][0], acc[rb_ + rt_][cb_ + c_]); \
                    acc[rb_ + rt_][cb_ + c_] = MFMA16(af[rt_][1], bfr[cb_ + c_][1], acc[rb_ + rt_][cb_ + c_]); \
                } \
            } \
        } \
        __builtin_amdgcn_s_setprio(0); \
        if ((STG) && (P) == 3) { asm volatile("s_waitcnt vmcnt(0)" ::: "memory"); } \
        __builtin_amdgcn_sched_barrier(0); \
        __builtin_amdgcn_s_barrier(); \
    } while (0)

#define KTILE(CUR, NXT, STG) do { \
        const ushortT* RS = &S[CUR][RSht][0]; \
        const ushortT* CS = &S[CUR][CSht][0]; \
        ushortT (*Snext)[8192] = S[NXT]; (void)Snext; \
        PHASE(0, STG); PHASE(1, STG); PHASE(2, STG); PHASE(3, STG); \
        koff += 64; \
    } while (0)

    // K = 1024 -> 16 K-tiles; kt parity picks buffer; stage kt+1 while
    // computing kt (drained at end of each staging tile). Last tile peeled.
#pragma unroll 1
    for (int it = 0; it < 7; ++it) { KTILE(0, 1, 1); KTILE(1, 0, 1); }
    KTILE(0, 1, 1);                                     // kt = 14 (drains kt15)
    KTILE(1, 0, 0);                                     // kt = 15
#undef KTILE
#undef PHASE
#undef STAGE_HT
}

// ---------------------------------------------------------------------------
// GEMM1: qkv projection, 256^2 tiles, 512 threads, 192 blocks (1/CU).
// q/k via swapped mainloop -> vectorized [b,h,l,d] stores; v via normal
// mainloop -> vectorized transposed [b,h,d,l] stores.
// ---------------------------------------------------------------------------
__global__ __launch_bounds__(512, 2) void gemm_qkv(
    const ushortT* __restrict__ A, const ushortT* __restrict__ Bt,
    const float* __restrict__ bias,
    ushortT* __restrict__ qb, ushortT* __restrict__ kb, ushortT* __restrict__ vt)
{
    __shared__ __align__(16) ushortT S[2][4][8192];   // 128 KiB
    const int tid = threadIdx.x;
    const int w = tid >> 6, lane = tid & 63, quad = lane >> 4, li = lane & 15;
    const int wm = w >> 2, wn = w & 3;
    // bijective XCD swizzle (192 % 8 == 0): each XCD gets 24 consecutive
    // tiles = 2 full M-panels -> A-panel L2 reuse.
    const int bid = blockIdx.x;
    const int nbid = (bid & 7) * 24 + (bid >> 3);
    const int bx = nbid % 12, by = nbid / 12;
    const int bm = by * 256, bn = bx * 256;
    const int which = bx >> 2;                        // 0=q 1=k 2=v (uniform)
    const f32x4 z4 = {0.f, 0.f, 0.f, 0.f};
    f32x4 acc[8][4];
#pragma unroll
    for (int i = 0; i < 8; ++i)
#pragma unroll
        for (int j = 0; j < 4; ++j) acc[i][j] = z4;

    if (which == 2) {
        mainloop256<false>(A, Bt, S, bm, bn, w, lane, acc);
#pragma unroll
        for (int rt = 0; rt < 8; ++rt) {
            const int m = bm + wm * 128 + (rt >> 2) * 64 + (rt & 3) * 16 + quad * 4;
            const int b = m >> 11, l = m & 2047;
#pragma unroll
            for (int ct = 0; ct < 4; ++ct) {
                const int n = bn + wn * 64 + 16 * ct + li;
                const int nn = n & 1023;
                const int h = nn >> 6, dd = nn & 63;
                const float bterm = bias[n];
                ushort4 o4;
                o4.x = f2bf(acc[rt][ct][0] + bterm);
                o4.y = f2bf(acc[rt][ct][1] + bterm);
                o4.z = f2bf(acc[rt][ct][2] + bterm);
                o4.w = f2bf(acc[rt][ct][3] + bterm);
                *(ushort4*)(vt + ((size_t)(b * NH + h) * DH + dd) * LSEQ + l) = o4;
            }
        }
    } else {
        mainloop256<true>(A, Bt, S, bm, bn, w, lane, acc);
        const float bscale = (which == 0) ? QSCALE : 1.0f;
        ushortT* dst = (which == 0) ? qb : kb;
#pragma unroll
        for (int rt = 0; rt < 8; ++rt) {
            const int n0 = bn + wm * 128 + (rt >> 2) * 64 + (rt & 3) * 16 + quad * 4;
            const int nn0 = n0 & 1023;
            const int h = nn0 >> 6, dd = nn0 & 63;
            const float4 bv = *(const float4*)&bias[n0];
#pragma unroll
            for (int ct = 0; ct < 4; ++ct) {
                const int m = bm + wn * 64 + 16 * ct + li;
                const int b = m >> 11, l = m & 2047;
                ushort4 o4;
                o4.x = f2bf(acc[rt][ct][0] + bv.x * bscale);
                o4.y = f2bf(acc[rt][ct][1] + bv.y * bscale);
                o4.z = f2bf(acc[rt][ct][2] + bv.z * bscale);
                o4.w = f2bf(acc[rt][ct][3] + bv.w * bscale);
                *(ushort4*)(dst + ((size_t)(b * NH + h) * LSEQ + l) * DH + dd) = o4;
            }
        }
    }
}

// ---------------------------------------------------------------------------
// GEMM2: out = o @ W_out + b_out (fp32 out). 128(M)x64(N) tiles, BK=128.
// R13: bijective XCD swizzle (512 blocks = 8 XCDs x [4 bm-rows x 16 bn]):
// per-XCD working set = A-panel 1 MB + full B 2 MB < 4 MB L2 (previously
// each XCD streamed all 8 MB of A).
// ---------------------------------------------------------------------------
__global__ __launch_bounds__(256) void gemm_out(
    const ushortT* __restrict__ A, const ushortT* __restrict__ Bt,
    const float* __restrict__ bias, float* __restrict__ out)
{
    __shared__ __align__(16) ushortT As[128 * 128];   // 32 KB
    __shared__ __align__(16) ushortT Bs[64 * 128];    // 16 KB
    const int tid = threadIdx.x;
    const int w = tid >> 6, lane = tid & 63, quad = lane >> 4, li = lane & 15;
    const int bid = blockIdx.x;
    const int xcd = bid & 7, sl = bid >> 3;           // xcd 0..7, sl 0..63
    const int bm = (xcd * 4 + (sl >> 4)) * 128;       // 4 bm-rows per XCD
    const int bn = (sl & 15) * 64;                    // all 16 bn per XCD
    const int wm = (w & 1) * 64, wn = (w >> 1) * 32;
    const int r4 = lane >> 4, c16 = lane & 15;
    const int sw = li & 7;

    const ushortT* pa[8]; ushortT* la[8];
#pragma unroll
    for (int j = 0; j < 8; ++j) {
        int Bi = w + 4 * j;
        int row = Bi * 4 + r4;
        int cxA = c16 ^ ((Bi & 1) * 4 + r4);       // == c16 ^ (row&7)
        pa[j] = A + (size_t)(bm + row) * DIMM + cxA * 8;
        la[j] = As + Bi * 512;
    }
    const ushortT* pb[4]; ushortT* lb[4];
#pragma unroll
    for (int j = 0; j < 4; ++j) {
        int Bi = w + 4 * j;
        int row = Bi * 4 + r4;
        int cxB = c16 ^ ((Bi & 1) * 4 + r4);
        pb[j] = Bt + (size_t)(bn + row) * DIMM + cxB * 8;
        lb[j] = Bs + Bi * 512;
    }

    const f32x4 z4 = {0.f, 0.f, 0.f, 0.f};
    f32x4 acc[4][2];
#pragma unroll
    for (int i = 0; i < 4; ++i) { acc[i][0] = z4; acc[i][1] = z4; }

    for (int k0 = 0; k0 < DIMM; k0 += 128) {
#pragma unroll
        for (int j = 0; j < 8; ++j) { gll16(pa[j], la[j]); pa[j] += 128; }
#pragma unroll
        for (int j = 0; j < 4; ++j) { gll16(pb[j], lb[j]); pb[j] += 128; }
        __syncthreads();
#pragma unroll
        for (int g = 0; g < 2; ++g) {
            const int s0 = (g * 8 + (quad ^ sw)) * 8;
            const int s1 = (g * 8 + ((quad + 4) ^ sw)) * 8;
            bf16x8 bfr[2][2];
#pragma unroll
            for (int t = 0; t < 2; ++t) {
                int R = wn + 16 * t + li;
                bfr[t][0] = *(const bf16x8*)&Bs[R * 128 + s0];
                bfr[t][1] = *(const bf16x8*)&Bs[R * 128 + s1];
            }
#pragma unroll
            for (int rt = 0; rt < 4; ++rt) {
                int R = wm + 16 * rt + li;
                bf16x8 a0 = *(const bf16x8*)&As[R * 128 + s0];
                bf16x8 a1 = *(const bf16x8*)&As[R * 128 + s1];
#pragma unroll
                for (int ct = 0; ct < 2; ++ct) {
                    acc[rt][ct] = MFMA16(a0, bfr[ct][0], acc[rt][ct]);
                    acc[rt][ct] = MFMA16(a1, bfr[ct][1], acc[rt][ct]);
                }
            }
        }
        __syncthreads();
    }
#pragma unroll
    for (int rt = 0; rt < 4; ++rt) {
#pragma unroll
        for (int ct = 0; ct < 2; ++ct) {
            int n = bn + wn + 16 * ct + li;
            float bterm = bias[n];
#pragma unroll
            for (int r = 0; r < 4; ++r) {
                int m = bm + wm + 16 * rt + quad * 4 + r;
                out[(size_t)m * DIMM + n] = acc[rt][ct][r] + bterm;
            }
        }
    }
}

// ---------------------------------------------------------------------------
// Flash attention, block-causal, transposed inner math, 128-KEY TILES.
// R9: softmax denominators via MFMA (A = ones, B = P^T fragments).
// R13: T5 setprio(1) around QK and PV/denom MFMA clusters, prio 0 during the
// exp2/pack VALU chain. attn waves free-run (no intra-t-loop barriers), so
// this is the measured role-split regime (+4-7%, m191/m214): while this wave
// does its serial exp-chain at prio 0, the co-resident wave's MFMAs win
// issue arbitration.
// Note: block->bh mapping already XCD-local for KV (bh ≡ blockIdx (mod 8)).
// ---------------------------------------------------------------------------
__global__ __launch_bounds__(256, 2) void attn(
    const ushortT* __restrict__ qg, const ushortT* __restrict__ kg,
    const ushortT* __restrict__ vtg, ushortT* __restrict__ og)
{
    __shared__ __align__(16) ushortT Kbuf[2][8192];   // [p][half*4096 + blk*512]
    __shared__ __align__(16) ushortT Vbuf[2][8192];   // [d][l] halves
    __shared__ __align__(16) ushortT PsT[4096];       // 4 waves x 2 KB

    const int tid = threadIdx.x;
    const int w = tid >> 6, lane = tid & 63, quad = lane >> 4, li = lane & 15;
    const int id = blockIdx.x;                 // 0..511
    const int qt = (id < 256) ? (15 - (id >> 5)) : ((id - 256) >> 5);
    const int bhid = id & 31;
    const int b = bhid >> 4, h = bhid & 15;
    const size_t bh = (size_t)b * NH + h;
    const ushortT* qbase = qg + (bh * LSEQ + qt * 128) * DH;
    const ushortT* kbase = kg + bh * LSEQ * DH;
    const ushortT* vbase = vtg + bh * DH * LSEQ;
    ushortT* obase = og + ((size_t)b * LSEQ + qt * 128) * DIMM + h * DH;
    const f32x4 z4 = {0.f, 0.f, 0.f, 0.f};

    // ones A-fragment for the denominator MFMA (bf16 1.0 = 0x3F80)
    const short ONE = (short)0x3F80;
    const bf16x8 onesA = {ONE, ONE, ONE, ONE, ONE, ONE, ONE, ONE};

    // staging lane geometry (within each 8-row x 1KB DMA block)
    const int r8 = lane >> 3, c8 = lane & 7, cx = c8 ^ r8;

    bf16x8 qf[2][2];
#pragma unroll
    for (int band = 0; band < 2; ++band) {
        int row = 32 * w + 16 * band + li;
        qf[band][0] = *(const bf16x8*)(qbase + (size_t)row * DH + quad * 8);
        qf[band][1] = *(const bf16x8*)(qbase + (size_t)row * DH + 32 + quad * 8);
    }
    f32x4 oaccT[2][4];     // [band][dt]: O^T, lane owns qrow=li
    f32x4 lsacc[2];        // denominator acc (all 4 comps equal per lane)
#pragma unroll
    for (int i = 0; i < 2; ++i) {
        lsacc[i] = z4;
#pragma unroll
        for (int j = 0; j < 4; ++j) oaccT[i][j] = z4;
    }

    const int nt = qt + 1;                 // 128-key tiles
    // stage tile 0 (8 gll16/wave: 2 halves x {K,V} x 2 blocks)
#pragma unroll
    for (int s = 0; s < 2; ++s)
#pragma unroll
        for (int jj = 0; jj < 2; ++jj) {
            int B = w + 4 * jj;
            gll16(kbase + (size_t)(s * 64 + B * 8 + r8) * DH + cx * 8,
                  &Kbuf[0][s * 4096 + B * 512]);
            gll16(vbase + (size_t)(B * 8 + r8) * LSEQ + s * 64 + cx * 8,
                  &Vbuf[0][s * 4096 + B * 512]);
        }
    __syncthreads();

    const int sw = li & 7;
    const int pbase = w * 1024 + li * 8;

    for (int t = 0; t < nt; ++t) {
        const int p = t & 1;
        if (t + 1 < nt) {   // DMA next 128-key tile; drains at loop barrier
#pragma unroll
            for (int s = 0; s < 2; ++s)
#pragma unroll
                for (int jj = 0; jj < 2; ++jj) {
                    int B = w + 4 * jj;
                    gll16(kbase + (size_t)((t + 1) * 128 + s * 64 + B * 8 + r8) * DH + cx * 8,
                          &Kbuf[1 - p][s * 4096 + B * 512]);
                    gll16(vbase + (size_t)(B * 8 + r8) * LSEQ + (t + 1) * 128 + s * 64 + cx * 8,
                          &Vbuf[1 - p][s * 4096 + B * 512]);
                }
        }

#pragma unroll
        for (int s = 0; s < 2; ++s) {
            const ushortT* Kb = &Kbuf[p][s * 4096];
            const ushortT* Vb = &Vbuf[p][s * 4096];
            bf16x8 kf[4][2], vf[4][2];
#pragma unroll
            for (int ct = 0; ct < 4; ++ct) {
                int R = 16 * ct + li;
                kf[ct][0] = *(const bf16x8*)&Kb[R * 64 + (quad ^ sw) * 8];
                kf[ct][1] = *(const bf16x8*)&Kb[R * 64 + ((quad + 4) ^ sw) * 8];
            }
#pragma unroll
            for (int dt = 0; dt < 4; ++dt) {
                int R = 16 * dt + li;
                vf[dt][0] = *(const bf16x8*)&Vb[R * 64 + (quad ^ sw) * 8];
                vf[dt][1] = *(const bf16x8*)&Vb[R * 64 + ((quad + 4) ^ sw) * 8];
            }
#pragma unroll
            for (int band = 0; band < 2; ++band) {
                // S^T = K Q^T (pre-scaled, log2 domain)
                f32x4 sa[4];
                __builtin_amdgcn_s_setprio(1);
#pragma unroll
                for (int ct = 0; ct < 4; ++ct) {
                    sa[ct] = MFMA16(kf[ct][0], qf[band][0], z4);
                    sa[ct] = MFMA16(kf[ct][1], qf[band][1], sa[ct]);
                }
                __builtin_amdgcn_s_setprio(0);
                // exp2, pack 4 keys (RTZ bf16) via v_perm, one b64 write
                // (prio 0: let the other wave's MFMAs win the pipe here)
#pragma unroll
                for (int ct = 0; ct < 4; ++ct) {
                    unsigned u0 = __float_as_uint(__builtin_amdgcn_exp2f(sa[ct][0]));
                    unsigned u1 = __float_as_uint(__builtin_amdgcn_exp2f(sa[ct][1]));
                    unsigned u2 = __float_as_uint(__builtin_amdgcn_exp2f(sa[ct][2]));
                    unsigned u3 = __float_as_uint(__builtin_amdgcn_exp2f(sa[ct][3]));
                    uint2 pk;
                    pk.x = __builtin_amdgcn_perm(u1, u0, 0x07060302u);
                    pk.y = __builtin_amdgcn_perm(u3, u2, 0x07060302u);
                    *(uint2*)&PsT[pbase + (2 * ct + (quad >> 1)) * 128 + (quad & 1) * 4] = pk;
                }
                // read P^T fragments once; use for BOTH denominator and PV
                bf16x8 pt0 = *(const bf16x8*)&PsT[pbase + quad * 128];
                bf16x8 pt1 = *(const bf16x8*)&PsT[pbase + (4 + quad) * 128];
                __builtin_amdgcn_s_setprio(1);
                lsacc[band] = MFMA16(onesA, pt0, lsacc[band]);   // denom += col-sums
                lsacc[band] = MFMA16(onesA, pt1, lsacc[band]);
#pragma unroll
                for (int dt = 0; dt < 4; ++dt) {
                    oaccT[band][dt] = MFMA16(vf[dt][0], pt0, oaccT[band][dt]);
                    oaccT[band][dt] = MFMA16(vf[dt][1], pt1, oaccT[band][dt]);
                }
                __builtin_amdgcn_s_setprio(0);
            }
        }
        __syncthreads();   // DMA drained + all readers of buf[p] done
    }

    // ---- normalize (denominator complete per-lane), store O (ushort4 on d) ----
#pragma unroll
    for (int band = 0; band < 2; ++band) {
        float inv = 1.0f / lsacc[band][0];
        int m = 32 * w + 16 * band + li;        // qrow
#pragma unroll
        for (int dt = 0; dt < 4; ++dt) {
            ushort4 o4;
            o4.x = f2bf(oaccT[band][dt][0] * inv);
            o4.y = f2bf(oaccT[band][dt][1] * inv);
            o4.z = f2bf(oaccT[band][dt][2] * inv);
            o4.w = f2bf(oaccT[band][dt][3] * inv);
            *(ushort4*)(obase + (size_t)m * DIMM + 16 * dt + quad * 4) = o4;
        }
    }
}

// ---------------------------------------------------------------------------
extern "C" void kernel_launch(void* const* d_in, const int* in_sizes, int n_in,
                              void* d_out, int out_size, void* d_ws, size_t ws_size,
                              hipStream_t stream)
{
    const float* x    = (const float*)d_in[0];
    const float* Wqkv = (const float*)d_in[1];
    const float* bqkv = (const float*)d_in[2];
    const float* Wout = (const float*)d_in[3];
    const float* bout = (const float*)d_in[4];

    const size_t M4 = (size_t)4 * 1024 * 1024;
    ushortT* ws  = (ushortT*)d_ws;
    ushortT* xb  = ws;                                  // 4M shorts
    ushortT* qb  = ws + M4;                             // 4M
    ushortT* kb  = ws + 2 * M4;                         // 4M
    ushortT* vt  = ws + 3 * M4;                         // 4M  [B,H,d,L]
    ushortT* ob  = ws + 4 * M4;                         // 4M  [B,L,H*d]
    ushortT* wqt = ws + 5 * M4;                         // 3M
    ushortT* wot = ws + 5 * M4 + (size_t)3 * 1024 * 1024;  // 1M

    prep<<<8192, 256, 0, stream>>>(x, xb, Wqkv, Wout, wqt, wot);
    gemm_qkv<<<dim3(192), 512, 0, stream>>>(xb, wqt, bqkv, qb, kb, vt);
    attn<<<dim3(512), 256, 0, stream>>>(qb, kb, vt, ob);
    gemm_out<<<dim3(512), 256, 0, stream>>>(ob, wot, bout, (float*)d_out);
}

// Round 5
// 165.843 us; speedup vs baseline: 1.0193x; 1.0119x over previous
//
#include <hip/hip_runtime.h>
#include <math.h>

#define BATCH 2
#define LSEQ  2048
#define DIMM  1024
#define NH    16
#define DH    64

typedef unsigned short ushortT;
typedef __attribute__((ext_vector_type(8))) short bf16x8;
typedef __attribute__((ext_vector_type(4))) float f32x4;

#define MFMA16(a, b, c) __builtin_amdgcn_mfma_f32_16x16x32_bf16((a), (b), (c), 0, 0, 0)

// scale folded into q columns of W_qkv: (1/sqrt(64)) * log2(e)
#define QSCALE 0.18033688011112042f

__device__ __forceinline__ ushortT f2bf(float f) {
    unsigned u = __float_as_uint(f);
    u += 0x7fffu + ((u >> 16) & 1u);   // RNE
    return (ushortT)(u >> 16);
}

// async global->LDS, 16B per lane. LDS dest is wave-uniform base + lane*16.
__device__ __forceinline__ void gll16(const ushortT* g, ushortT* l) {
    ushortT* gm = const_cast<ushortT*>(g);
    __builtin_amdgcn_global_load_lds(
        (__attribute__((address_space(1))) void*)gm,
        (__attribute__((address_space(3))) void*)l, 16, 0, 0);
}

// ---------------------------------------------------------------------------
// Fused prep: blocks [0,4096): x fp32->bf16; blocks [4096,8192): weight
// transposes W[K][N] fp32 -> Wt[N][K] bf16 (q-cols of W_qkv scaled by QSCALE).
// ---------------------------------------------------------------------------
__global__ __launch_bounds__(256) void prep(
    const float* __restrict__ x, ushortT* __restrict__ xb,
    const float* __restrict__ Wqkv, const float* __restrict__ Wout,
    ushortT* __restrict__ wqt, ushortT* __restrict__ wot)
{
    __shared__ float T[32][33];
    const int bx = blockIdx.x;
    const int tid = threadIdx.x;
    if (bx < 4096) {
        int i = bx * 256 + tid;
        float4 v = ((const float4*)x)[i];
        ushort4 o;
        o.x = f2bf(v.x); o.y = f2bf(v.y); o.z = f2bf(v.z); o.w = f2bf(v.w);
        ((ushort4*)xb)[i] = o;
        return;
    }
    const int id2 = bx - 4096;
    const int nb = id2 & 127, kb = id2 >> 7;
    const float* W; ushortT* Wt; int N, n0, nlimit;
    if (nb < 96) { W = Wqkv; Wt = wqt; N = 3 * DIMM; n0 = nb * 32; nlimit = DIMM; }
    else         { W = Wout; Wt = wot; N = DIMM;     n0 = (nb - 96) * 32; nlimit = 0; }
    const int k0 = kb * 32;
    const int c = tid & 31, r0 = tid >> 5;
#pragma unroll
    for (int p = 0; p < 4; ++p)
        T[r0 + 8 * p][c] = W[(size_t)(k0 + r0 + 8 * p) * N + n0 + c];
    __syncthreads();
#pragma unroll
    for (int p = 0; p < 4; ++p) {
        int rr = r0 + 8 * p;
        float v = T[c][rr];
        if (n0 + rr < nlimit) v *= QSCALE;
        Wt[(size_t)(n0 + rr) * DIMM + k0 + c] = f2bf(v);
    }
}

// ---------------------------------------------------------------------------
// R14: one-barrier-per-K-tile mainloop, compiler-scheduled interior.
// R11-R13 post-mortem: the 4-phase structure serialized an LDS read burst
// (8 waves x 12 ds_read_b128 = 768 cyc LDS-pipe) against a coarse
// lgkmcnt(0) every phase, plus 8 barriers/tile -> ~1500 cyc/phase, MfmaUtil
// ~20%. The hand-rolled waits PREVENTED the fine-grained lgkmcnt(4/3/1/0)
// interleave the compiler emits natively (m97 asm observation).
// v3: per K-tile: {issue all 8 staging DMAs FIRST (whole compute to land) |
// all 24 ds_reads + 64 MFMA, compiler-interleaved | __syncthreads (drains
// vmcnt+lgkm, flips buffers)}. 1 barrier/tile instead of 8; zero manual
// waits. Per-element accumulation order identical to R11 (s0 then s1).
// 256x256, 8 waves (2M x 4N), BK=64, 128 KiB LDS double-buffer, half-tiles
// ht0/1 = A rows 0-127/128-255, ht2/3 = B rows 0-127/128-255.
// ---------------------------------------------------------------------------
template<bool SWAP>
__device__ __forceinline__ void mainloop256(
    const ushortT* __restrict__ A, const ushortT* __restrict__ Bt,
    ushortT S[2][4][8192], int bm, int bn, int w, int lane, f32x4 acc[8][4])
{
    const int quad = lane >> 4, li = lane & 15;
    const int wm = w >> 2, wn = w & 3;
    const int sw = li & 7;
    const int s0 = (quad ^ sw) * 8, s1 = ((quad + 4) ^ sw) * 8;
    const int r8 = lane >> 3, c8 = lane & 7, cch = c8 ^ r8;
    const ushortT* sA = A  + (size_t)(bm + 16 * w + r8) * DIMM + cch * 8;
    const ushortT* sB = Bt + (size_t)(bn + 16 * w + r8) * DIMM + cch * 8;
    const int RSht = SWAP ? 2 + wm : wm;          // row-operand half-tile
    const int CSht = SWAP ? (wn >> 1) : 2 + (wn >> 1);  // col-operand half-tile
    const int cb64 = (wn & 1) * 64;               // row base within CS half-tile
    const int ld0 = (16 * w) * 64, ld1 = (16 * w + 8) * 64;

    {   // prologue: stage K-tile 0 into S[0], full drain (one-time)
#pragma unroll
        for (int P = 0; P < 4; ++P) {
            const ushortT* sp = ((P < 2) ? sA : sB) + (P & 1) * 128 * DIMM;
            gll16(sp,            &S[0][P][ld0]);
            gll16(sp + 8 * DIMM, &S[0][P][ld1]);
        }
        __syncthreads();
    }

#pragma unroll 1
    for (int kt = 0; kt < 16; ++kt) {
        const int cur = kt & 1;
        if (kt < 15) {   // stage K-tile kt+1 into the other buffer, issue-first
            const int koff = (kt + 1) * 64;
#pragma unroll
            for (int P = 0; P < 4; ++P) {
                const ushortT* sp = ((P < 2) ? sA : sB) + (P & 1) * 128 * DIMM + koff;
                gll16(sp,            &S[cur ^ 1][P][ld0]);
                gll16(sp + 8 * DIMM, &S[cur ^ 1][P][ld1]);
            }
        }
        const ushortT* RS = &S[cur][RSht][0];
        const ushortT* CS = &S[cur][CSht][0];
        bf16x8 bfr[4][2];
#pragma unroll
        for (int ct = 0; ct < 4; ++ct) {
            const int R = cb64 + 16 * ct + li;
            bfr[ct][0] = *(const bf16x8*)&CS[R * 64 + s0];
            bfr[ct][1] = *(const bf16x8*)&CS[R * 64 + s1];
        }
#pragma unroll
        for (int half = 0; half < 2; ++half) {
            bf16x8 af[4][2];
#pragma unroll
            for (int rt = 0; rt < 4; ++rt) {
                const int R = half * 64 + 16 * rt + li;
                af[rt][0] = *(const bf16x8*)&RS[R * 64 + s0];
                af[rt][1] = *(const bf16x8*)&RS[R * 64 + s1];
            }
#pragma unroll
            for (int rt = 0; rt < 4; ++rt) {
#pragma unroll
                for (int ct = 0; ct < 4; ++ct) {
                    acc[half * 4 + rt][ct] = MFMA16(af[rt][0], bfr[ct][0], acc[half * 4 + rt][ct]);
                    acc[half * 4 + rt][ct] = MFMA16(af[rt][1], bfr[ct][1], acc[half * 4 + rt][ct]);
                }
            }
        }
        __syncthreads();   // drains staging DMAs (issued ~full tile ago) + LDS
    }
}

// ---------------------------------------------------------------------------
// GEMM1: qkv projection, 256^2 tiles, 512 threads, 192 blocks (1/CU).
// q/k via swapped mainloop -> vectorized [b,h,l,d] stores; v via normal
// mainloop -> vectorized transposed [b,h,d,l] stores.
// ---------------------------------------------------------------------------
__global__ __launch_bounds__(512, 2) void gemm_qkv(
    const ushortT* __restrict__ A, const ushortT* __restrict__ Bt,
    const float* __restrict__ bias,
    ushortT* __restrict__ qb, ushortT* __restrict__ kb, ushortT* __restrict__ vt)
{
    __shared__ __align__(16) ushortT S[2][4][8192];   // 128 KiB
    const int tid = threadIdx.x;
    const int w = tid >> 6, lane = tid & 63, quad = lane >> 4, li = lane & 15;
    const int wm = w >> 2, wn = w & 3;
    // bijective XCD swizzle (192 % 8 == 0): each XCD gets 24 consecutive
    // tiles = 2 full M-panels -> A-panel L2 reuse.
    const int bid = blockIdx.x;
    const int nbid = (bid & 7) * 24 + (bid >> 3);
    const int bx = nbid % 12, by = nbid / 12;
    const int bm = by * 256, bn = bx * 256;
    const int which = bx >> 2;                        // 0=q 1=k 2=v (uniform)
    const f32x4 z4 = {0.f, 0.f, 0.f, 0.f};
    f32x4 acc[8][4];
#pragma unroll
    for (int i = 0; i < 8; ++i)
#pragma unroll
        for (int j = 0; j < 4; ++j) acc[i][j] = z4;

    if (which == 2) {
        mainloop256<false>(A, Bt, S, bm, bn, w, lane, acc);
#pragma unroll
        for (int rt = 0; rt < 8; ++rt) {
            const int m = bm + wm * 128 + (rt >> 2) * 64 + (rt & 3) * 16 + quad * 4;
            const int b = m >> 11, l = m & 2047;
#pragma unroll
            for (int ct = 0; ct < 4; ++ct) {
                const int n = bn + wn * 64 + 16 * ct + li;
                const int nn = n & 1023;
                const int h = nn >> 6, dd = nn & 63;
                const float bterm = bias[n];
                ushort4 o4;
                o4.x = f2bf(acc[rt][ct][0] + bterm);
                o4.y = f2bf(acc[rt][ct][1] + bterm);
                o4.z = f2bf(acc[rt][ct][2] + bterm);
                o4.w = f2bf(acc[rt][ct][3] + bterm);
                *(ushort4*)(vt + ((size_t)(b * NH + h) * DH + dd) * LSEQ + l) = o4;
            }
        }
    } else {
        mainloop256<true>(A, Bt, S, bm, bn, w, lane, acc);
        const float bscale = (which == 0) ? QSCALE : 1.0f;
        ushortT* dst = (which == 0) ? qb : kb;
#pragma unroll
        for (int rt = 0; rt < 8; ++rt) {
            const int n0 = bn + wm * 128 + (rt >> 2) * 64 + (rt & 3) * 16 + quad * 4;
            const int nn0 = n0 & 1023;
            const int h = nn0 >> 6, dd = nn0 & 63;
            const float4 bv = *(const float4*)&bias[n0];
#pragma unroll
            for (int ct = 0; ct < 4; ++ct) {
                const int m = bm + wn * 64 + 16 * ct + li;
                const int b = m >> 11, l = m & 2047;
                ushort4 o4;
                o4.x = f2bf(acc[rt][ct][0] + bv.x * bscale);
                o4.y = f2bf(acc[rt][ct][1] + bv.y * bscale);
                o4.z = f2bf(acc[rt][ct][2] + bv.z * bscale);
                o4.w = f2bf(acc[rt][ct][3] + bv.w * bscale);
                *(ushort4*)(dst + ((size_t)(b * NH + h) * LSEQ + l) * DH + dd) = o4;
            }
        }
    }
}

// ---------------------------------------------------------------------------
// GEMM2: out = o @ W_out + b_out (fp32 out). 128(M)x64(N) tiles, BK=128.
// R13: bijective XCD swizzle (512 blocks = 8 XCDs x [4 bm-rows x 16 bn]):
// per-XCD working set = A-panel 1 MB + full B 2 MB < 4 MB L2.
// ---------------------------------------------------------------------------
__global__ __launch_bounds__(256) void gemm_out(
    const ushortT* __restrict__ A, const ushortT* __restrict__ Bt,
    const float* __restrict__ bias, float* __restrict__ out)
{
    __shared__ __align__(16) ushortT As[128 * 128];   // 32 KB
    __shared__ __align__(16) ushortT Bs[64 * 128];    // 16 KB
    const int tid = threadIdx.x;
    const int w = tid >> 6, lane = tid & 63, quad = lane >> 4, li = lane & 15;
    const int bid = blockIdx.x;
    const int xcd = bid & 7, sl = bid >> 3;           // xcd 0..7, sl 0..63
    const int bm = (xcd * 4 + (sl >> 4)) * 128;       // 4 bm-rows per XCD
    const int bn = (sl & 15) * 64;                    // all 16 bn per XCD
    const int wm = (w & 1) * 64, wn = (w >> 1) * 32;
    const int r4 = lane >> 4, c16 = lane & 15;
    const int sw = li & 7;

    const ushortT* pa[8]; ushortT* la[8];
#pragma unroll
    for (int j = 0; j < 8; ++j) {
        int Bi = w + 4 * j;
        int row = Bi * 4 + r4;
        int cxA = c16 ^ ((Bi & 1) * 4 + r4);       // == c16 ^ (row&7)
        pa[j] = A + (size_t)(bm + row) * DIMM + cxA * 8;
        la[j] = As + Bi * 512;
    }
    const ushortT* pb[4]; ushortT* lb[4];
#pragma unroll
    for (int j = 0; j < 4; ++j) {
        int Bi = w + 4 * j;
        int row = Bi * 4 + r4;
        int cxB = c16 ^ ((Bi & 1) * 4 + r4);
        pb[j] = Bt + (size_t)(bn + row) * DIMM + cxB * 8;
        lb[j] = Bs + Bi * 512;
    }

    const f32x4 z4 = {0.f, 0.f, 0.f, 0.f};
    f32x4 acc[4][2];
#pragma unroll
    for (int i = 0; i < 4; ++i) { acc[i][0] = z4; acc[i][1] = z4; }

    for (int k0 = 0; k0 < DIMM; k0 += 128) {
#pragma unroll
        for (int j = 0; j < 8; ++j) { gll16(pa[j], la[j]); pa[j] += 128; }
#pragma unroll
        for (int j = 0; j < 4; ++j) { gll16(pb[j], lb[j]); pb[j] += 128; }
        __syncthreads();
#pragma unroll
        for (int g = 0; g < 2; ++g) {
            const int s0 = (g * 8 + (quad ^ sw)) * 8;
            const int s1 = (g * 8 + ((quad + 4) ^ sw)) * 8;
            bf16x8 bfr[2][2];
#pragma unroll
            for (int t = 0; t < 2; ++t) {
                int R = wn + 16 * t + li;
                bfr[t][0] = *(const bf16x8*)&Bs[R * 128 + s0];
                bfr[t][1] = *(const bf16x8*)&Bs[R * 128 + s1];
            }
#pragma unroll
            for (int rt = 0; rt < 4; ++rt) {
                int R = wm + 16 * rt + li;
                bf16x8 a0 = *(const bf16x8*)&As[R * 128 + s0];
                bf16x8 a1 = *(const bf16x8*)&As[R * 128 + s1];
#pragma unroll
                for (int ct = 0; ct < 2; ++ct) {
                    acc[rt][ct] = MFMA16(a0, bfr[ct][0], acc[rt][ct]);
                    acc[rt][ct] = MFMA16(a1, bfr[ct][1], acc[rt][ct]);
                }
            }
        }
        __syncthreads();
    }
#pragma unroll
    for (int rt = 0; rt < 4; ++rt) {
#pragma unroll
        for (int ct = 0; ct < 2; ++ct) {
            int n = bn + wn + 16 * ct + li;
            float bterm = bias[n];
#pragma unroll
            for (int r = 0; r < 4; ++r) {
                int m = bm + wm + 16 * rt + quad * 4 + r;
                out[(size_t)m * DIMM + n] = acc[rt][ct][r] + bterm;
            }
        }
    }
}

// ---------------------------------------------------------------------------
// Flash attention, block-causal, transposed inner math, 128-KEY TILES.
// R9: softmax denominators via MFMA (A = ones, B = P^T fragments).
// R13: T5 setprio around MFMA clusters (kept; harmless).
// ---------------------------------------------------------------------------
__global__ __launch_bounds__(256, 2) void attn(
    const ushortT* __restrict__ qg, const ushortT* __restrict__ kg,
    const ushortT* __restrict__ vtg, ushortT* __restrict__ og)
{
    __shared__ __align__(16) ushortT Kbuf[2][8192];   // [p][half*4096 + blk*512]
    __shared__ __align__(16) ushortT Vbuf[2][8192];   // [d][l] halves
    __shared__ __align__(16) ushortT PsT[4096];       // 4 waves x 2 KB

    const int tid = threadIdx.x;
    const int w = tid >> 6, lane = tid & 63, quad = lane >> 4, li = lane & 15;
    const int id = blockIdx.x;                 // 0..511
    const int qt = (id < 256) ? (15 - (id >> 5)) : ((id - 256) >> 5);
    const int bhid = id & 31;
    const int b = bhid >> 4, h = bhid & 15;
    const size_t bh = (size_t)b * NH + h;
    const ushortT* qbase = qg + (bh * LSEQ + qt * 128) * DH;
    const ushortT* kbase = kg + bh * LSEQ * DH;
    const ushortT* vbase = vtg + bh * DH * LSEQ;
    ushortT* obase = og + ((size_t)b * LSEQ + qt * 128) * DIMM + h * DH;
    const f32x4 z4 = {0.f, 0.f, 0.f, 0.f};

    // ones A-fragment for the denominator MFMA (bf16 1.0 = 0x3F80)
    const short ONE = (short)0x3F80;
    const bf16x8 onesA = {ONE, ONE, ONE, ONE, ONE, ONE, ONE, ONE};

    // staging lane geometry (within each 8-row x 1KB DMA block)
    const int r8 = lane >> 3, c8 = lane & 7, cx = c8 ^ r8;

    bf16x8 qf[2][2];
#pragma unroll
    for (int band = 0; band < 2; ++band) {
        int row = 32 * w + 16 * band + li;
        qf[band][0] = *(const bf16x8*)(qbase + (size_t)row * DH + quad * 8);
        qf[band][1] = *(const bf16x8*)(qbase + (size_t)row * DH + 32 + quad * 8);
    }
    f32x4 oaccT[2][4];     // [band][dt]: O^T, lane owns qrow=li
    f32x4 lsacc[2];        // denominator acc (all 4 comps equal per lane)
#pragma unroll
    for (int i = 0; i < 2; ++i) {
        lsacc[i] = z4;
#pragma unroll
        for (int j = 0; j < 4; ++j) oaccT[i][j] = z4;
    }

    const int nt = qt + 1;                 // 128-key tiles
    // stage tile 0 (8 gll16/wave: 2 halves x {K,V} x 2 blocks)
#pragma unroll
    for (int s = 0; s < 2; ++s)
#pragma unroll
        for (int jj = 0; jj < 2; ++jj) {
            int B = w + 4 * jj;
            gll16(kbase + (size_t)(s * 64 + B * 8 + r8) * DH + cx * 8,
                  &Kbuf[0][s * 4096 + B * 512]);
            gll16(vbase + (size_t)(B * 8 + r8) * LSEQ + s * 64 + cx * 8,
                  &Vbuf[0][s * 4096 + B * 512]);
        }
    __syncthreads();

    const int sw = li & 7;
    const int pbase = w * 1024 + li * 8;

    for (int t = 0; t < nt; ++t) {
        const int p = t & 1;
        if (t + 1 < nt) {   // DMA next 128-key tile; drains at loop barrier
#pragma unroll
            for (int s = 0; s < 2; ++s)
#pragma unroll
                for (int jj = 0; jj < 2; ++jj) {
                    int B = w + 4 * jj;
                    gll16(kbase + (size_t)((t + 1) * 128 + s * 64 + B * 8 + r8) * DH + cx * 8,
                          &Kbuf[1 - p][s * 4096 + B * 512]);
                    gll16(vbase + (size_t)(B * 8 + r8) * LSEQ + (t + 1) * 128 + s * 64 + cx * 8,
                          &Vbuf[1 - p][s * 4096 + B * 512]);
                }
        }

#pragma unroll
        for (int s = 0; s < 2; ++s) {
            const ushortT* Kb = &Kbuf[p][s * 4096];
            const ushortT* Vb = &Vbuf[p][s * 4096];
            bf16x8 kf[4][2], vf[4][2];
#pragma unroll
            for (int ct = 0; ct < 4; ++ct) {
                int R = 16 * ct + li;
                kf[ct][0] = *(const bf16x8*)&Kb[R * 64 + (quad ^ sw) * 8];
                kf[ct][1] = *(const bf16x8*)&Kb[R * 64 + ((quad + 4) ^ sw) * 8];
            }
#pragma unroll
            for (int dt = 0; dt < 4; ++dt) {
                int R = 16 * dt + li;
                vf[dt][0] = *(const bf16x8*)&Vb[R * 64 + (quad ^ sw) * 8];
                vf[dt][1] = *(const bf16x8*)&Vb[R * 64 + ((quad + 4) ^ sw) * 8];
            }
#pragma unroll
            for (int band = 0; band < 2; ++band) {
                // S^T = K Q^T (pre-scaled, log2 domain)
                f32x4 sa[4];
                __builtin_amdgcn_s_setprio(1);
#pragma unroll
                for (int ct = 0; ct < 4; ++ct) {
                    sa[ct] = MFMA16(kf[ct][0], qf[band][0], z4);
                    sa[ct] = MFMA16(kf[ct][1], qf[band][1], sa[ct]);
                }
                __builtin_amdgcn_s_setprio(0);
                // exp2, pack 4 keys (RTZ bf16) via v_perm, one b64 write
#pragma unroll
                for (int ct = 0; ct < 4; ++ct) {
                    unsigned u0 = __float_as_uint(__builtin_amdgcn_exp2f(sa[ct][0]));
                    unsigned u1 = __float_as_uint(__builtin_amdgcn_exp2f(sa[ct][1]));
                    unsigned u2 = __float_as_uint(__builtin_amdgcn_exp2f(sa[ct][2]));
                    unsigned u3 = __float_as_uint(__builtin_amdgcn_exp2f(sa[ct][3]));
                    uint2 pk;
                    pk.x = __builtin_amdgcn_perm(u1, u0, 0x07060302u);
                    pk.y = __builtin_amdgcn_perm(u3, u2, 0x07060302u);
                    *(uint2*)&PsT[pbase + (2 * ct + (quad >> 1)) * 128 + (quad & 1) * 4] = pk;
                }
                // read P^T fragments once; use for BOTH denominator and PV
                bf16x8 pt0 = *(const bf16x8*)&PsT[pbase + quad * 128];
                bf16x8 pt1 = *(const bf16x8*)&PsT[pbase + (4 + quad) * 128];
                __builtin_amdgcn_s_setprio(1);
                lsacc[band] = MFMA16(onesA, pt0, lsacc[band]);   // denom += col-sums
                lsacc[band] = MFMA16(onesA, pt1, lsacc[band]);
#pragma unroll
                for (int dt = 0; dt < 4; ++dt) {
                    oaccT[band][dt] = MFMA16(vf[dt][0], pt0, oaccT[band][dt]);
                    oaccT[band][dt] = MFMA16(vf[dt][1], pt1, oaccT[band][dt]);
                }
                __builtin_amdgcn_s_setprio(0);
            }
        }
        __syncthreads();   // DMA drained + all readers of buf[p] done
    }

    // ---- normalize (denominator complete per-lane), store O (ushort4 on d) ----
#pragma unroll
    for (int band = 0; band < 2; ++band) {
        float inv = 1.0f / lsacc[band][0];
        int m = 32 * w + 16 * band + li;        // qrow
#pragma unroll
        for (int dt = 0; dt < 4; ++dt) {
            ushort4 o4;
            o4.x = f2bf(oaccT[band][dt][0] * inv);
            o4.y = f2bf(oaccT[band][dt][1] * inv);
            o4.z = f2bf(oaccT[band][dt][2] * inv);
            o4.w = f2bf(oaccT[band][dt][3] * inv);
            *(ushort4*)(obase + (size_t)m * DIMM + 16 * dt + quad * 4) = o4;
        }
    }
}

// ---------------------------------------------------------------------------
extern "C" void kernel_launch(void* const* d_in, const int* in_sizes, int n_in,
                              void* d_out, int out_size, void* d_ws, size_t ws_size,
                              hipStream_t stream)
{
    const float* x    = (const float*)d_in[0];
    const float* Wqkv = (const float*)d_in[1];
    const float* bqkv = (const float*)d_in[2];
    const float* Wout = (const float*)d_in[3];
    const float* bout = (const float*)d_in[4];

    const size_t M4 = (size_t)4 * 1024 * 1024;
    ushortT* ws  = (ushortT*)d_ws;
    ushortT* xb  = ws;                                  // 4M shorts
    ushortT* qb  = ws + M4;                             // 4M
    ushortT* kb  = ws + 2 * M4;                         // 4M
    ushortT* vt  = ws + 3 * M4;                         // 4M  [B,H,d,L]
    ushortT* ob  = ws + 4 * M4;                         // 4M  [B,L,H*d]
    ushortT* wqt = ws + 5 * M4;                         // 3M
    ushortT* wot = ws + 5 * M4 + (size_t)3 * 1024 * 1024;  // 1M

    prep<<<8192, 256, 0, stream>>>(x, xb, Wqkv, Wout, wqt, wot);
    gemm_qkv<<<dim3(192), 512, 0, stream>>>(xb, wqt, bqkv, qb, kb, vt);
    attn<<<dim3(512), 256, 0, stream>>>(qb, kb, vt, ob);
    gemm_out<<<dim3(512), 256, 0, stream>>>(ob, wot, bout, (float*)d_out);
}